// Round 7
// baseline (312.780 us; speedup 1.0000x reference)
//
#include <hip/hip_runtime.h>
#include <math.h>

// NoisyTopkRouter via f16-split MFMA (hi + lo*2^-11 planes, 3 passes).
// R7: barrier-free main. R6 post-mortem: main was latency-bound (all pipes
// ~11%) on per-chunk barrier + L2-latency-exposed B loads + LDS conflicts.
// Fix: A-fragments loaded DIRECTLY from global per-lane (lane reads
// x[tok0 + (lane&15)][kc + (lane>>4)*8 .. +8] = 32 B; wave footprint =
// 16 full 128-B lines; 4-wave redundancy is L1-absorbed) -> no LDS, no
// barriers, every wave free-runs. M-tile = 16 tokens, grid 2048 = 8
// blocks/CU, launch_bounds(256,5) for ~20 waves/CU latency hiding.
// x prefetched one chunk ahead in registers. Numerics byte-identical to
// the PASSING R6 pipeline (same split/MFMA/fp64-fold/zpart/epilogue).
// d_ws: 1 MB wt3 + 16 MB zpart.

typedef _Float16 f16x8 __attribute__((ext_vector_type(8)));
typedef float f32x4 __attribute__((ext_vector_type(4)));

constexpr int ND = 2048, NE = 64, NK = 8, NTOK = 16384;
constexpr int KC   = 32;          // k per chunk (one MFMA K)
constexpr int NCHT = ND / KC;     // 64 chunks total
constexpr int KS   = 2;           // K-split ways
constexpr int CPS  = NCHT / KS;   // 32 chunks per segment
constexpr int MTOK = 16;          // tokens per block (one M-tile)

// ---- prep: W1|W2 -> f16 hi / lo*2^11 planes in MFMA B-fragment order.
// frag(cg, p, t) at ((cg*2+p)*8 + t)*512 + lane*8; t 0-3: W1 cols, 4-7: W2.
__global__ void prep_w(const float* __restrict__ W1, const float* __restrict__ W2,
                       _Float16* __restrict__ wt3) {
    const int g    = blockIdx.x * 256 + threadIdx.x;   // 0..32767
    const int cg   = g >> 9;
    const int rem  = g & 511;
    const int t    = rem >> 6;
    const int lane = rem & 63;
    const int col  = lane & 15, q = lane >> 4;
    const int n    = t * 16 + col;
    const float* W = (t < 4) ? W1 : W2;
    const int cn   = n & 63;
    _Float16 h[8], l[8];
    #pragma unroll
    for (int j = 0; j < 8; ++j) {
        const float v = W[(size_t)(cg * 32 + q * 8 + j) * 64 + cn];
        const _Float16 hh = (_Float16)v;
        h[j] = hh;
        l[j] = (_Float16)((v - (float)hh) * 2048.0f);   // pre-scaled lo plane
    }
    *(f16x8*)&wt3[((size_t)(cg * 2 + 0) * 8 + t) * 512 + lane * 8] = *(f16x8*)h;
    *(f16x8*)&wt3[((size_t)(cg * 2 + 1) * 8 + t) * 512 + lane * 8] = *(f16x8*)l;
}

// ---- main: per block 16 tokens x 128 cols x K=1024 (one kseg). No LDS.
__global__ __launch_bounds__(256, 5)
void router_main(const float* __restrict__ x, const _Float16* __restrict__ wt3,
                 float* __restrict__ zpart) {
    const int tid  = threadIdx.x;
    const int lane = tid & 63;
    const int wu   = __builtin_amdgcn_readfirstlane(tid >> 6);
    const int col  = lane & 15, q = lane >> 4;
    const int mg   = blockIdx.x >> 1;          // 0..1023 token group
    const int ks   = blockIdx.x & 1;           // k segment
    const long tok0 = (long)mg * MTOK;
    const int c0   = ks * CPS;
    const int ta   = 2 * wu;                   // this wave's first N-tile

    // per-lane A source: row = its token (col), k-octet = q
    const float* xrow = x + (tok0 + col) * (size_t)ND + (size_t)c0 * KC + q * 8;

    f32x4 a0[2], a1[2];
    double zm[2][4];
    #pragma unroll
    for (int i = 0; i < 2; ++i)
        #pragma unroll
        for (int r = 0; r < 4; ++r) { a0[i][r] = 0.f; a1[i][r] = 0.f; zm[i][r] = 0.0; }

    float4 xa = *(const float4*)(xrow);
    float4 xb = *(const float4*)(xrow + 4);

    for (int c = 0; c < CPS; ++c) {
        // B fragments straight from global (wt3 1 MB, L2-hot, coalesced dwordx4)
        const size_t fb = (size_t)(c0 + c) * 8192 + (size_t)lane * 8;
        const f16x8 bha = *(const f16x8*)&wt3[fb + ta * 512];
        const f16x8 bhb = *(const f16x8*)&wt3[fb + (ta + 1) * 512];
        const f16x8 bla = *(const f16x8*)&wt3[fb + 4096 + ta * 512];
        const f16x8 blb = *(const f16x8*)&wt3[fb + 4096 + (ta + 1) * 512];

        // next chunk's x flies across this chunk's compute
        float4 na, nb;
        if (c + 1 < CPS) {
            na = *(const float4*)(xrow + (c + 1) * KC);
            nb = *(const float4*)(xrow + (c + 1) * KC + 4);
        }

        // split x -> f16 hi/lo A-fragments (A[m=col][k=q*8+j])
        const float xf[8] = {xa.x, xa.y, xa.z, xa.w, xb.x, xb.y, xb.z, xb.w};
        f16x8 ah, al;
        #pragma unroll
        for (int j = 0; j < 8; ++j) {
            const _Float16 h = (_Float16)xf[j];
            ah[j] = h;
            al[j] = (_Float16)((xf[j] - (float)h) * 2048.0f);
        }

        a0[0] = __builtin_amdgcn_mfma_f32_16x16x32_f16(ah, bha, a0[0], 0, 0, 0);
        a0[1] = __builtin_amdgcn_mfma_f32_16x16x32_f16(ah, bhb, a0[1], 0, 0, 0);
        a1[0] = __builtin_amdgcn_mfma_f32_16x16x32_f16(ah, bla, a1[0], 0, 0, 0);
        a1[1] = __builtin_amdgcn_mfma_f32_16x16x32_f16(ah, blb, a1[1], 0, 0, 0);
        a1[0] = __builtin_amdgcn_mfma_f32_16x16x32_f16(al, bha, a1[0], 0, 0, 0);
        a1[1] = __builtin_amdgcn_mfma_f32_16x16x32_f16(al, bhb, a1[1], 0, 0, 0);

        xa = na; xb = nb;

        if ((c & 7) == 7) {           // fold every K=256 into fp64 (as R6)
            #pragma unroll
            for (int i = 0; i < 2; ++i)
                #pragma unroll
                for (int r = 0; r < 4; ++r) {
                    zm[i][r] += (double)a0[i][r]
                              + (double)(a1[i][r] * 4.8828125e-4f);   // 2^-11
                    a0[i][r] = 0.f; a1[i][r] = 0.f;
                }
        }
    }

    // store kseg partial slice. C/D layout: n = tile*16 + (lane&15), m = q*4+r
    float* zp = zpart + (size_t)ks * NTOK * 128;
    #pragma unroll
    for (int i = 0; i < 2; ++i) {
        const int n = (ta + i) * 16 + col;
        #pragma unroll
        for (int r = 0; r < 4; ++r) {
            const long token = tok0 + q * 4 + r;
            zp[(size_t)token * 128 + n] = (float)zm[i][r];
        }
    }
}

// ---- epilogue: combine ksegs (fp64), softplus, softmax/top8/masked softmax.
__global__ __launch_bounds__(256, 4)
void router_epi(const float* __restrict__ zpart, const float* __restrict__ noise,
                const float* __restrict__ b1, const float* __restrict__ b2,
                float* __restrict__ out_sparse, float* __restrict__ out_idx,
                float* __restrict__ out_full) {
    const int lane = threadIdx.x & 63;
    const int wu   = threadIdx.x >> 6;
    const float b1v = b1[lane];
    const float b2v = b2[lane];

    for (int tt = 0; tt < 4; ++tt) {
        const long tok = (long)blockIdx.x * 16 + wu * 4 + tt;
        const size_t r0 = (size_t)tok * 128;
        const size_t s1 = (size_t)NTOK * 128;
        const double z1d = (double)zpart[r0 + lane]      + (double)zpart[s1 + r0 + lane];
        const double z2d = (double)zpart[r0 + 64 + lane] + (double)zpart[s1 + r0 + 64 + lane];
        const float z1 = (float)z1d + b1v;
        const float z2 = (float)z2d + b2v;
        const float sc = (float)log1p(exp((double)z2));   // f64 softplus
        const float nz = noise[tok * NE + lane];
        const float mixed = z1 + nz * sc;

        // full softmax across the wave (lane = expert)
        float vmax = mixed;
        for (int off = 32; off; off >>= 1) vmax = fmaxf(vmax, __shfl_xor(vmax, off));
        const float e = expf(mixed - vmax);
        float denom = e;
        for (int off = 32; off; off >>= 1) denom += __shfl_xor(denom, off);
        const float fullv = e / denom;

        // top-8 iterative butterfly argmax, tie-break lowest index
        float cur = mixed;
        int   sel = 0;
        float myidxf = 0.0f;
        #pragma unroll
        for (int r = 0; r < NK; ++r) {
            float bv = cur; int bi = lane;
            for (int off = 32; off; off >>= 1) {
                const float ov = __shfl_xor(bv, off);
                const int   oi = __shfl_xor(bi, off);
                if (ov > bv || (ov == bv && oi < bi)) { bv = ov; bi = oi; }
            }
            if (lane == r)  myidxf = (float)bi;
            if (lane == bi) { sel = 1; cur = -INFINITY; }
        }

        const float es = sel ? e : 0.0f;
        float dsum = es;
        for (int off = 32; off; off >>= 1) dsum += __shfl_xor(dsum, off);
        const float sparsev = sel ? (e / dsum) : 0.0f;

        out_full[tok * NE + lane]   = fullv;
        out_sparse[tok * NE + lane] = sparsev;
        if (lane < NK) out_idx[tok * NK + lane] = myidxf;
    }
}

extern "C" void kernel_launch(void* const* d_in, const int* in_sizes, int n_in,
                              void* d_out, int out_size, void* d_ws, size_t ws_size,
                              hipStream_t stream) {
    const float* x     = (const float*)d_in[0];
    const float* noise = (const float*)d_in[1];
    const float* W1    = (const float*)d_in[2];
    const float* b1    = (const float*)d_in[3];
    const float* W2    = (const float*)d_in[4];
    const float* b2    = (const float*)d_in[5];

    float* out_sparse = (float*)d_out;                      // [16384*64]
    float* out_idx    = out_sparse + (size_t)NTOK * NE;     // [16384*8]
    float* out_full   = out_idx + (size_t)NTOK * NK;        // [16384*64]

    _Float16* wt3 = (_Float16*)d_ws;                              // 1 MB fragment-order W
    float* zpart  = (float*)((char*)d_ws + ((size_t)1 << 20));    // 16 MB [2][16384][128]

    prep_w<<<128, 256, 0, stream>>>(W1, W2, wt3);
    router_main<<<NTOK / MTOK * KS, 256, 0, stream>>>(x, wt3, zpart);   // 2048 blocks
    router_epi<<<NTOK / 16, 256, 0, stream>>>(zpart, noise, b1, b2,
                                              out_sparse, out_idx, out_full);
}